// Round 7
// baseline (812.515 us; speedup 1.0000x reference)
//
#include <hip/hip_runtime.h>
#include <hip/hip_bf16.h>
#include <cstdint>
#include <cstddef>

// ---------- helpers ----------
__device__ __forceinline__ float bf2f(unsigned short u) {
    return __uint_as_float(((unsigned int)u) << 16);
}
__device__ __forceinline__ unsigned short f2bf(float f) {
    unsigned int u = __float_as_uint(f);
    unsigned int r = (u + 0x7fff + ((u >> 16) & 1)) >> 16;
    return (unsigned short)r;
}

using bf16x8 = __attribute__((ext_vector_type(8))) short;
using f32x4  = __attribute__((ext_vector_type(4))) float;
typedef float f32x2 __attribute__((ext_vector_type(2)));

// fp8 (HW format, e4m3 on gfx950) helpers — scale S=64 folded in producer/consumer
#define FP8_SCALE    64.0f
#define FP8_INVSCALE 0.015625f

__device__ __forceinline__ unsigned char f2fp8(float v) {
    int p = __builtin_amdgcn_cvt_pk_fp8_f32(v, v, 0, false);
    return (unsigned char)(p & 0xFF);
}
__device__ __forceinline__ void acc_fp8x8(unsigned lo, unsigned hi, float* a) {
    f32x2 f0 = __builtin_amdgcn_cvt_pk_f32_fp8((int)lo, false);
    f32x2 f1 = __builtin_amdgcn_cvt_pk_f32_fp8((int)lo, true);
    f32x2 f2 = __builtin_amdgcn_cvt_pk_f32_fp8((int)hi, false);
    f32x2 f3 = __builtin_amdgcn_cvt_pk_f32_fp8((int)hi, true);
    a[0] += f0[0]; a[1] += f0[1]; a[2] += f1[0]; a[3] += f1[1];
    a[4] += f2[0]; a[5] += f2[1]; a[6] += f3[0]; a[7] += f3[1];
}
__device__ __forceinline__ void acc_fp8x16(uint4 v, float* a) {
    acc_fp8x8(v.x, v.y, a);
    acc_fp8x8(v.z, v.w, a + 8);
}

// packed fp32->bf16 (RTNE, same rounding as f2bf) — 1 inst per 2 floats
__device__ __forceinline__ bf16x8 cvt8(float4 a, float4 b) {
    union { unsigned u[4]; bf16x8 v; } r;
    asm("v_cvt_pk_bf16_f32 %0, %1, %2" : "=v"(r.u[0]) : "v"(a.x), "v"(a.y));
    asm("v_cvt_pk_bf16_f32 %0, %1, %2" : "=v"(r.u[1]) : "v"(a.z), "v"(a.w));
    asm("v_cvt_pk_bf16_f32 %0, %1, %2" : "=v"(r.u[2]) : "v"(b.x), "v"(b.y));
    asm("v_cvt_pk_bf16_f32 %0, %1, %2" : "=v"(r.u[3]) : "v"(b.z), "v"(b.w));
    return r.v;
}

// ---------- bucketed CSR build ----------
#define BKT_SHIFT 9
#define BKT_NODES 512
#define BKT_CAP   18432
#define BIN_TILE  4096
#define PAD_G     8                       // degree padding granularity
#define BKT_PADMAX (BKT_NODES * (PAD_G - 1))  // worst-case pad per bucket

// packed entry: (src << 9) | dst_local  (requires n < 2^23)
__global__ __launch_bounds__(256) void bin_kernel(const int* __restrict__ eidx, int E,
                                                  int nb, int ntiles,
                                                  int* __restrict__ gcur,
                                                  unsigned* __restrict__ binned) {
    __shared__ int cnt[256];
    __shared__ int base[256];
    const int tid = threadIdx.x;
    for (int t = blockIdx.x; t < ntiles; t += gridDim.x) {
        cnt[tid] = 0;
        __syncthreads();
        int s[16], d[16];
        unsigned pk[16];  // (b << 16) | rank ; 0xFFFFFFFF = invalid
        #pragma unroll
        for (int j = 0; j < 16; ++j) {
            int e = t * BIN_TILE + j * 256 + tid;
            if (e < E) {
                s[j] = eidx[e];
                d[j] = eidx[E + e];
                int b = d[j] >> BKT_SHIFT;
                int r = atomicAdd(&cnt[b], 1);
                pk[j] = ((unsigned)b << 16) | (unsigned)r;
            } else {
                pk[j] = 0xFFFFFFFFu;
            }
        }
        __syncthreads();
        if (tid < nb) {
            int c = cnt[tid];
            base[tid] = c ? atomicAdd(&gcur[tid], c) : 0;
        }
        __syncthreads();
        #pragma unroll
        for (int j = 0; j < 16; ++j) {
            if (pk[j] != 0xFFFFFFFFu) {
                int b = (int)(pk[j] >> 16);
                int pos = base[b] + (int)(pk[j] & 0xFFFFu);
                if (pos < BKT_CAP)
                    binned[(size_t)b * BKT_CAP + pos] =
                        ((unsigned)s[j] << BKT_SHIFT) | ((unsigned)d[j] & (BKT_NODES - 1));
            }
        }
        __syncthreads();
    }
}

// fused: bucket-base scan (padded worst-case, redundant per block) + per-bucket
// histogram + local scan with degree padding to PAD_G -> rowptr, pdeg (in deg[]),
// dinv, csr_src (pad slots get sentinel src = n -> zeroed feature row).
// Row ends come from deg[node], NOT rowptr[node+1] (bucket regions have gaps).
__global__ __launch_bounds__(256) void csr_build_kernel(const unsigned* __restrict__ binned,
                                                        const int* __restrict__ gcur,
                                                        int* __restrict__ rowptr,
                                                        int* __restrict__ deg,
                                                        float* __restrict__ dinv,
                                                        int* __restrict__ csr_src,
                                                        int nb, int n) {
    __shared__ int cnt[BKT_NODES];
    __shared__ int sbase[256];
    __shared__ int wsum[4];
    const int b = blockIdx.x;
    const int base_node = b << BKT_SHIFT;
    const int tid = threadIdx.x, lane = tid & 63, wave = tid >> 6;

    // bucket-base exclusive scan over padded-worst-case bucket sizes
    int c = (tid < nb) ? (min(gcur[tid], BKT_CAP) + BKT_PADMAX) : 0;
    int inc = c;
    #pragma unroll
    for (int off = 1; off < 64; off <<= 1) {
        int t = __shfl_up(inc, off, 64);
        if (lane >= off) inc += t;
    }
    if (lane == 63) wsum[wave] = inc;
    __syncthreads();
    int wbase = 0;
    #pragma unroll
    for (int w = 0; w < 4; ++w)
        if (w < wave) wbase += wsum[w];
    sbase[tid] = wbase + inc - c;
    __syncthreads();
    const int gb = sbase[b];
    __syncthreads();

    // per-bucket histogram (real counts)
    for (int i = tid; i < BKT_NODES; i += 256) cnt[i] = 0;
    __syncthreads();
    const int m = min(gcur[b], BKT_CAP);
    const unsigned* eb = binned + (size_t)b * BKT_CAP;
    for (int i = tid; i < m; i += 256)
        atomicAdd(&cnt[eb[i] & (BKT_NODES - 1)], 1);
    __syncthreads();

    // local scan over PADDED counts (2 elems/thread) -> rowptr, deg, dinv, cursors
    int c0 = cnt[2 * tid], c1 = cnt[2 * tid + 1];
    int pc0 = (c0 + PAD_G - 1) & ~(PAD_G - 1);
    int pc1 = (c1 + PAD_G - 1) & ~(PAD_G - 1);
    int s = pc0 + pc1;
    int inc2 = s;
    #pragma unroll
    for (int off = 1; off < 64; off <<= 1) {
        int t = __shfl_up(inc2, off, 64);
        if (lane >= off) inc2 += t;
    }
    __syncthreads();  // wsum reuse
    if (lane == 63) wsum[wave] = inc2;
    __syncthreads();
    int wbase2 = 0;
    #pragma unroll
    for (int w = 0; w < 4; ++w)
        if (w < wave) wbase2 += wsum[w];
    int excl = wbase2 + inc2 - s;
    int node0 = base_node + 2 * tid;
    int st0 = gb + excl, st1 = gb + excl + pc0;
    if (node0 < n) {
        rowptr[node0] = st0;
        deg[node0] = pc0;
        dinv[node0] = rsqrtf((float)c0 + 1.0f);
        // pad-slot fill with sentinel (zero-row) src = n
        for (int q = c0; q < pc0; ++q) csr_src[st0 + q] = n;
    }
    if (node0 + 1 < n) {
        rowptr[node0 + 1] = st1;
        deg[node0 + 1] = pc1;
        dinv[node0 + 1] = rsqrtf((float)c1 + 1.0f);
        for (int q = c1; q < pc1; ++q) csr_src[st1 + q] = n;
    }
    __syncthreads();
    cnt[2 * tid] = st0;
    cnt[2 * tid + 1] = st1;
    __syncthreads();

    // fill real entries
    for (int i = tid; i < m; i += 256) {
        unsigned p = eb[i];
        int pos = atomicAdd(&cnt[p & (BKT_NODES - 1)], 1);
        csr_src[pos] = (int)(p >> BKT_SHIFT);
    }
}

// ---------- fallback CSR build (tight rows; deg = true degree) ----------
__global__ __launch_bounds__(256) void hist_kernel(const int* __restrict__ dst, int E,
                                                   int* __restrict__ deg) {
    int i = blockIdx.x * blockDim.x + threadIdx.x;
    int stride = gridDim.x * blockDim.x;
    for (int e = i; e < E; e += stride) atomicAdd(&deg[dst[e]], 1);
}

__global__ __launch_bounds__(256) void fill_kernel(const int* __restrict__ eidx, int E,
                                                   int* __restrict__ cursor,
                                                   int* __restrict__ csr_src) {
    int e = blockIdx.x * blockDim.x + threadIdx.x;
    if (e < E) {
        int s = eidx[e];
        int d = eidx[E + e];
        int pos = atomicAdd(&cursor[d], 1);
        csr_src[pos] = s;
    }
}

__global__ __launch_bounds__(256) void scan_kernel(const int* __restrict__ deg,
                                                   int* __restrict__ rowptr, int n) {
    __shared__ int wsum[4];
    __shared__ int carry_s;
    int tid = threadIdx.x, lane = tid & 63, wave = tid >> 6;
    if (tid == 0) carry_s = 0;
    __syncthreads();
    const int CHUNK = 16;
    const int PER_ITER = 256 * CHUNK;
    for (int base = 0; base < n; base += PER_ITER) {
        int idx0 = base + tid * CHUNK;
        int v[CHUNK];
        int s = 0;
        #pragma unroll
        for (int j = 0; j < CHUNK; ++j) {
            int i = idx0 + j;
            v[j] = (i < n) ? deg[i] : 0;
            s += v[j];
        }
        int inc = s;
        #pragma unroll
        for (int off = 1; off < 64; off <<= 1) {
            int t = __shfl_up(inc, off, 64);
            if (lane >= off) inc += t;
        }
        if (lane == 63) wsum[wave] = inc;
        __syncthreads();
        int wbase = 0;
        #pragma unroll
        for (int w = 0; w < 4; ++w)
            if (w < wave) wbase += wsum[w];
        int total_iter = wsum[0] + wsum[1] + wsum[2] + wsum[3];
        int carry = carry_s;
        __syncthreads();
        if (tid == 0) carry_s = carry + total_iter;
        int run = carry + wbase + (inc - s);
        #pragma unroll
        for (int j = 0; j < CHUNK; ++j) {
            int i = idx0 + j;
            if (i < n) rowptr[i] = run;
            run += v[j];
        }
        __syncthreads();
    }
    if (tid == 0) rowptr[n] = carry_s;
}

__global__ __launch_bounds__(256) void dinv_kernel(const int* __restrict__ deg,
                                                   float* __restrict__ dinv, int n) {
    int i = blockIdx.x * blockDim.x + threadIdx.x;
    if (i < n) dinv[i] = rsqrtf((float)deg[i] + 1.0f);
}

// ---------- weight fragment-pack + sentinel-row zeroing (one launch) ----------
// WF layout: block blk = (k0/32)*(N/16) + f   (512 shorts/block)
//   within block: lane*8 + jj where lane = quad*16 + l16
//   element = W[k0 + quad*8 + jj][f*16 + l16]
// Consumer: bfr = WF + (blk << 9) + lane*8  -> one coalesced 16B load per lane.
__global__ __launch_bounds__(256) void wt_kernel(const float* __restrict__ W1,
                                                 const float* __restrict__ W2,
                                                 unsigned short* __restrict__ W1F,
                                                 unsigned short* __restrict__ W2F,
                                                 unsigned char* __restrict__ hA_sent,
                                                 unsigned char* __restrict__ hB_sent) {
    int i = blockIdx.x * 256 + threadIdx.x;
    const int n1 = 512 * 256;
    if (i < n1) {
        // W1F: K=512, N=256, 16 blocks per k0
        int blk = i >> 9, r = i & 511;
        int lane = r >> 3, jj = r & 7;
        int k0 = (blk >> 4) << 5;
        int f = blk & 15;
        int quad = lane >> 4, l16 = lane & 15;
        int k = k0 + quad * 8 + jj;
        int nn = f * 16 + l16;
        W1F[i] = f2bf(W1[(size_t)k * 256 + nn]);
    } else {
        int j = i - n1;
        if (j < 256 * 128) {
            // W2F: K=256, N=128, 8 blocks per k0
            int blk = j >> 9, r = j & 511;
            int lane = r >> 3, jj = r & 7;
            int k0 = (blk >> 3) << 5;
            int f = blk & 7;
            int quad = lane >> 4, l16 = lane & 15;
            int k = k0 + quad * 8 + jj;
            int nn = f * 16 + l16;
            W2F[j] = f2bf(W2[(size_t)k * 128 + nn]);
        }
    }
    // sentinel zero rows (gather target for CSR pad slots)
    if (blockIdx.x == 0) {
        if (threadIdx.x < 256) hA_sent[threadIdx.x] = 0;
        if (threadIdx.x < 128) hB_sent[threadIdx.x] = 0;
    }
}

// ---------- GEMM1: hs1[M,256](fp8, * dinv * 64) = x[M,512] @ W1 ----------
// 2-phase pipelined, N-split waves: each wave owns a 64(M) x 64(N) tile so each
// B-fragment is reused by 4 A-fragments. A (fp32) staged to LDS via
// global_load_lds (dbuf, XOR-swizzled src+read).
__global__ __launch_bounds__(256, 4) void gemm1_kernel(const float* __restrict__ x,
                                                       const unsigned short* __restrict__ W1F,
                                                       const float* __restrict__ dinv,
                                                       unsigned char* __restrict__ C,
                                                       int M) {
    __shared__ float As[2][4096];  // 2 x (64 rows x 64 floats) = 2 x 16 KB
    const int tid = threadIdx.x;
    const int wave = tid >> 6, lane = tid & 63;
    const int quad = lane >> 4, l16 = lane & 15;
    const int m0 = blockIdx.x * 64;

    // staging sources: unit = wave*4+c covers LDS rows unit*4..unit*4+3;
    // lane l stages dest byte unit*1024 + l*16 (HW: uniform base + lane*16).
    const float* sbase[4];
    #pragma unroll
    for (int c = 0; c < 4; ++c) {
        int row  = (wave * 4 + c) * 4 + (lane >> 4);
        int grow = min(m0 + row, M - 1);
        int scb  = ((lane & 15) << 4) ^ ((row & 7) << 4);  // pre-swizzled col byte
        sbase[c] = x + (size_t)grow * 512 + (scb >> 2);
    }
    // fragment-read swizzle (row = am*16 + l16; am*16 % 8 == 0 -> row&7 == l16&7)
    const int swz = (l16 & 7) << 4;

    // prologue: stage k-step 0 into buf 0
    #pragma unroll
    for (int c = 0; c < 4; ++c)
        __builtin_amdgcn_global_load_lds(sbase[c], &As[0][(wave * 4 + c) * 256], 16, 0, 0);
    __syncthreads();

    f32x4 acc[4][4] = {};  // [am][bn]
    for (int t = 0; t < 8; ++t) {
        const int cur = t & 1;
        if (t < 7) {  // issue next stage BEFORE compute (overlap)
            #pragma unroll
            for (int c = 0; c < 4; ++c)
                __builtin_amdgcn_global_load_lds(sbase[c] + (t + 1) * 64,
                                                 &As[cur ^ 1][(wave * 4 + c) * 256], 16, 0, 0);
        }
        const char* ab = reinterpret_cast<const char*>(&As[cur][0]);
        #pragma unroll
        for (int ks = 0; ks < 2; ++ks) {
            const int cb = (ks << 7) + (quad << 5);
            // 4 B-fragments for this wave's N-slice (cols wave*64 .. +63)
            const unsigned short* wp =
                W1F + (((((t << 1) + ks) << 4) + (wave << 2)) << 9) + lane * 8;
            bf16x8 bfr0 = *reinterpret_cast<const bf16x8*>(wp);
            bf16x8 bfr1 = *reinterpret_cast<const bf16x8*>(wp + 512);
            bf16x8 bfr2 = *reinterpret_cast<const bf16x8*>(wp + 1024);
            bf16x8 bfr3 = *reinterpret_cast<const bf16x8*>(wp + 1536);
            #pragma unroll
            for (int am = 0; am < 4; ++am) {
                const char* rp = ab + ((am * 16 + l16) << 8);
                float4 a0 = *reinterpret_cast<const float4*>(rp + (cb ^ swz));
                float4 a1 = *reinterpret_cast<const float4*>(rp + ((cb + 16) ^ swz));
                bf16x8 af = cvt8(a0, a1);
                acc[am][0] = __builtin_amdgcn_mfma_f32_16x16x32_bf16(af, bfr0, acc[am][0], 0, 0, 0);
                acc[am][1] = __builtin_amdgcn_mfma_f32_16x16x32_bf16(af, bfr1, acc[am][1], 0, 0, 0);
                acc[am][2] = __builtin_amdgcn_mfma_f32_16x16x32_bf16(af, bfr2, acc[am][2], 0, 0, 0);
                acc[am][3] = __builtin_amdgcn_mfma_f32_16x16x32_bf16(af, bfr3, acc[am][3], 0, 0, 0);
            }
        }
        __syncthreads();  // drains in-flight stage + protects buf reuse
    }

    #pragma unroll
    for (int am = 0; am < 4; ++am) {
        #pragma unroll
        for (int rr = 0; rr < 4; ++rr) {
            int row = m0 + am * 16 + quad * 4 + rr;
            if (row < M) {
                float dv = dinv[row] * FP8_SCALE;
                #pragma unroll
                for (int bn = 0; bn < 4; ++bn)
                    C[(size_t)row * 256 + wave * 64 + bn * 16 + l16] =
                        f2fp8(acc[am][bn][rr] * dv);
            }
        }
    }
}

// ---------- fused agg1 + gemm2 ----------
__device__ __forceinline__ int a2_idx(int row, int col) {
    int byte = (row << 9) + (col << 1);
    byte ^= (row & 7) << 4;
    return byte >> 1;
}

__global__ __launch_bounds__(256, 4) void agg1_gemm2_kernel(const unsigned char* __restrict__ hs1,
                                                            const float* __restrict__ dinv,
                                                            const int* __restrict__ rowptr,
                                                            const int* __restrict__ deg,
                                                            const int* __restrict__ csr_src,
                                                            const float* __restrict__ b1,
                                                            const unsigned short* __restrict__ W2F,
                                                            unsigned char* __restrict__ hs2,
                                                            int n) {
    __shared__ __align__(16) short As2[64 * 256];  // 32 KB exact
    const int tid = threadIdx.x;
    const int m0 = blockIdx.x * 64;

    // ---- phase 1: gather (16 lanes/node, 16 feats/lane via uint4 16B loads) ----
    {
        const int lane = tid & 15;
        const int sub = tid >> 4;  // 0..15
        const unsigned char* tab = hs1 + (size_t)lane * 16;
        const float4* bp = reinterpret_cast<const float4*>(b1) + lane * 4;
        float4 bq0 = bp[0], bq1 = bp[1], bq2 = bp[2], bq3 = bp[3];
        float bvals[16] = {bq0.x, bq0.y, bq0.z, bq0.w, bq1.x, bq1.y, bq1.z, bq1.w,
                           bq2.x, bq2.y, bq2.z, bq2.w, bq3.x, bq3.y, bq3.z, bq3.w};
        for (int g = 0; g < 4; ++g) {
            int row = g * 16 + sub;
            int node = m0 + row;
            float h[16] = {};
            if (node < n) {
                float a[16] = {};
                uint4 v0 = *reinterpret_cast<const uint4*>(tab + (size_t)node * 256);
                acc_fp8x16(v0, a);  // self term
                int e0 = rowptr[node], e1 = e0 + deg[node];
                int p = e0;
                for (; p + 8 <= e1; p += 8) {
                    int s[8];
                    #pragma unroll
                    for (int u = 0; u < 8; ++u) s[u] = csr_src[p + u];
                    uint4 w[8];
                    #pragma unroll
                    for (int u = 0; u < 8; ++u)
                        w[u] = *reinterpret_cast<const uint4*>(tab + (size_t)s[u] * 256);
                    #pragma unroll
                    for (int u = 0; u < 8; ++u)
                        acc_fp8x16(w[u], a);
                }
                for (; p < e1; ++p) {  // only on fallback (unpadded) CSR
                    int s = csr_src[p];
                    uint4 w = *reinterpret_cast<const uint4*>(tab + (size_t)s * 256);
                    acc_fp8x16(w, a);
                }
                float dv = dinv[node] * FP8_INVSCALE;
                #pragma unroll
                for (int j = 0; j < 16; ++j)
                    h[j] = fmaxf(fmaf(a[j], dv, bvals[j]), 0.f);
            }
            bf16x8 o0, o1;
            #pragma unroll
            for (int j = 0; j < 8; ++j) {
                o0[j] = (short)f2bf(h[j]);
                o1[j] = (short)f2bf(h[j + 8]);
            }
            *reinterpret_cast<bf16x8*>(&As2[a2_idx(row, lane * 16)]) = o0;
            *reinterpret_cast<bf16x8*>(&As2[a2_idx(row, lane * 16 + 8)]) = o1;
        }
    }
    __syncthreads();

    // ---- phase 2: MFMA K=256, N=128, B direct from W2F, no barriers ----
    const int wave = tid >> 6, lane = tid & 63;
    const int quad = lane >> 4, l16 = lane & 15;
    const int arow = wave * 16 + l16;
    f32x4 acc[2][4] = {};
    #pragma unroll
    for (int k0 = 0; k0 < 256; k0 += 32) {
        bf16x8 af = *reinterpret_cast<const bf16x8*>(&As2[a2_idx(arow, k0 + quad * 8)]);
        #pragma unroll
        for (int i = 0; i < 2; ++i) {
            #pragma unroll
            for (int ct = 0; ct < 4; ++ct) {
                bf16x8 bfr = *reinterpret_cast<const bf16x8*>(
                    W2F + ((((k0 >> 5) << 3) + i * 4 + ct) << 9) + lane * 8);
                acc[i][ct] = __builtin_amdgcn_mfma_f32_16x16x32_bf16(af, bfr, acc[i][ct], 0, 0, 0);
            }
        }
    }
    #pragma unroll
    for (int r = 0; r < 4; ++r) {
        int row = m0 + wave * 16 + quad * 4 + r;
        if (row < n) {
            float dv = dinv[row] * FP8_SCALE;
            #pragma unroll
            for (int i = 0; i < 2; ++i)
                #pragma unroll
                for (int ct = 0; ct < 4; ++ct)
                    hs2[(size_t)row * 128 + i * 64 + ct * 16 + l16] =
                        f2fp8(acc[i][ct][r] * dv);
        }
    }
}

// ---------- agg layer 2 + fused head (fp8 hs2, 8 lanes/node via uint4) ----------
__global__ __launch_bounds__(256) void agg2_head_kernel(const unsigned char* __restrict__ hs,
                                                        const float* __restrict__ dinv,
                                                        const int* __restrict__ rowptr,
                                                        const int* __restrict__ deg,
                                                        const int* __restrict__ csr_src,
                                                        const float* __restrict__ bias,
                                                        const float* __restrict__ Wl,
                                                        const float* __restrict__ bl,
                                                        float* __restrict__ out, int n) {
    constexpr int LANES = 8, H = 128, NPB = 32;
    int sub = threadIdx.x / LANES;
    int lane = threadIdx.x % LANES;
    int node = blockIdx.x * NPB + sub;
    if (node >= n) return;
    const unsigned char* tab = hs + (size_t)lane * 16;
    float a[16] = {};
    uint4 v0 = *reinterpret_cast<const uint4*>(tab + (size_t)node * H);
    acc_fp8x16(v0, a);  // self term
    int e0 = rowptr[node], e1 = e0 + deg[node];
    int p = e0;
    for (; p + 8 <= e1; p += 8) {
        int s[8];
        #pragma unroll
        for (int u = 0; u < 8; ++u) s[u] = csr_src[p + u];
        uint4 w[8];
        #pragma unroll
        for (int u = 0; u < 8; ++u)
            w[u] = *reinterpret_cast<const uint4*>(tab + (size_t)s[u] * H);
        #pragma unroll
        for (int u = 0; u < 8; ++u)
            acc_fp8x16(w[u], a);
    }
    for (; p < e1; ++p) {  // only on fallback CSR
        int s = csr_src[p];
        uint4 w = *reinterpret_cast<const uint4*>(tab + (size_t)s * H);
        acc_fp8x16(w, a);
    }
    float dv = dinv[node] * FP8_INVSCALE;
    const float4* bp = reinterpret_cast<const float4*>(bias) + lane * 4;
    float4 bq0 = bp[0], bq1 = bp[1], bq2 = bp[2], bq3 = bp[3];
    float bvals[16] = {bq0.x, bq0.y, bq0.z, bq0.w, bq1.x, bq1.y, bq1.z, bq1.w,
                       bq2.x, bq2.y, bq2.z, bq2.w, bq3.x, bq3.y, bq3.z, bq3.w};
    float h[16];
    #pragma unroll
    for (int j = 0; j < 16; ++j)
        h[j] = fmaxf(fmaf(a[j], dv, bvals[j]), 0.f);
    float p0 = 0.f, p1 = 0.f, p2 = 0.f, p3 = 0.f;
    #pragma unroll
    for (int j = 0; j < 16; ++j) {
        float4 w = *reinterpret_cast<const float4*>(Wl + (size_t)(lane * 16 + j) * 4);
        p0 = fmaf(h[j], w.x, p0); p1 = fmaf(h[j], w.y, p1);
        p2 = fmaf(h[j], w.z, p2); p3 = fmaf(h[j], w.w, p3);
    }
    #pragma unroll
    for (int m = 1; m < 8; m <<= 1) {
        p0 += __shfl_xor(p0, m, 8);
        p1 += __shfl_xor(p1, m, 8);
        p2 += __shfl_xor(p2, m, 8);
        p3 += __shfl_xor(p3, m, 8);
    }
    if (lane == 0) {
        p0 += bl[0]; p1 += bl[1]; p2 += bl[2]; p3 += bl[3];
        float mx = fmaxf(fmaxf(p0, p1), fmaxf(p2, p3));
        float s = __expf(p0 - mx) + __expf(p1 - mx) + __expf(p2 - mx) + __expf(p3 - mx);
        float lse = mx + __logf(s);
        *(reinterpret_cast<float4*>(out) + node) = make_float4(p0 - lse, p1 - lse, p2 - lse, p3 - lse);
    }
}

// ---------- launch ----------
extern "C" void kernel_launch(void* const* d_in, const int* in_sizes, int n_in,
                              void* d_out, int out_size, void* d_ws, size_t ws_size,
                              hipStream_t stream) {
    const float* x  = (const float*)d_in[0];
    const int* eidx = (const int*)d_in[1];
    const float* W1 = (const float*)d_in[2];
    const float* b1 = (const float*)d_in[3];
    const float* W2 = (const float*)d_in[4];
    const float* b2 = (const float*)d_in[5];
    const float* Wl = (const float*)d_in[6];
    const float* bl = (const float*)d_in[7];
    float* out = (float*)d_out;

    const int n = in_sizes[0] / 512;
    const int E = in_sizes[1] / 2;
    const int nb = (n + BKT_NODES - 1) >> BKT_SHIFT;  // 196 for n=100000

    char* ws = (char*)d_ws;
    size_t off = 0;
    auto alloc = [&](size_t bytes) -> void* {
        void* p = ws + off;
        off += (bytes + 255) & ~(size_t)255;
        return p;
    };
    unsigned char*  hA  = (unsigned char*)alloc((size_t)(n + 1) * 256);  // hs1 fp8 + zero row
    unsigned char*  hB  = (unsigned char*)alloc((size_t)(n + 1) * 128);  // hs2 fp8 + zero row
    unsigned short* W1F = (unsigned short*)alloc((size_t)256 * 512 * 2);
    unsigned short* W2F = (unsigned short*)alloc((size_t)128 * 256 * 2);
    int* deg     = (int*)alloc((size_t)n * 4);
    int* rowptr  = (int*)alloc(((size_t)n + 1) * 4);
    int* cursor  = (int*)alloc((size_t)n * 4);
    float* dinv  = (float*)alloc((size_t)n * 4);
    int* csr_src = (int*)alloc(((size_t)E + (size_t)nb * BKT_PADMAX + 64) * 4);
    int* gcur    = (int*)alloc((size_t)nb * 4);
    size_t need_binned = off + (size_t)nb * BKT_CAP * 4 + 256;
    unsigned* binned = (unsigned*)alloc((size_t)nb * BKT_CAP * 4);

    if (need_binned <= ws_size && nb <= 256 && n < (1 << 23)) {
        hipMemsetAsync(gcur, 0, (size_t)nb * 4, stream);
        int ntiles = (E + BIN_TILE - 1) / BIN_TILE;
        int bgrid = ntiles < 1024 ? ntiles : 1024;
        bin_kernel<<<dim3(bgrid), dim3(256), 0, stream>>>(eidx, E, nb, ntiles, gcur, binned);
        csr_build_kernel<<<dim3(nb), dim3(256), 0, stream>>>(binned, gcur, rowptr, deg, dinv,
                                                             csr_src, nb, n);
    } else {
        hipMemsetAsync(deg, 0, (size_t)n * 4, stream);
        hist_kernel<<<dim3(1024), dim3(256), 0, stream>>>(eidx + E, E, deg);
        scan_kernel<<<dim3(1), dim3(256), 0, stream>>>(deg, rowptr, n);
        dinv_kernel<<<dim3((n + 255) / 256), dim3(256), 0, stream>>>(deg, dinv, n);
        hipMemcpyAsync(cursor, rowptr, (size_t)n * 4, hipMemcpyDeviceToDevice, stream);
        fill_kernel<<<dim3((E + 255) / 256), dim3(256), 0, stream>>>(eidx, E, cursor, csr_src);
    }

    // Weight fragment-pack + sentinel-row zeroing (single launch)
    wt_kernel<<<dim3((512 * 256 + 256 * 128 + 255) / 256), dim3(256), 0, stream>>>(
        W1, W2, W1F, W2F, hA + (size_t)n * 256, hB + (size_t)n * 128);

    const int mblocks = (n + 63) / 64;

    // Layer 1 GEMM: hs1 = fp8((x@W1)*dinv*64)   (2-phase pipelined, N-split waves)
    gemm1_kernel<<<dim3(mblocks), dim3(256), 0, stream>>>(x, W1F, dinv, hA, n);

    // Fused agg1 + gemm2: hs2 = fp8((relu(agg(hs1))@W2)*dinv*64)
    agg1_gemm2_kernel<<<dim3(mblocks), dim3(256), 0, stream>>>(
        hA, dinv, rowptr, deg, csr_src, b1, W2F, hB, n);

    // agg2 + head fused (fp8 gather, 8 lanes/node)
    agg2_head_kernel<<<dim3((n + 31) / 32), dim3(256), 0, stream>>>(
        hB, dinv, rowptr, deg, csr_src, b2, Wl, bl, out, n);
}

// Round 8
// 604.421 us; speedup vs baseline: 1.3443x; 1.3443x over previous
//
#include <hip/hip_runtime.h>
#include <hip/hip_bf16.h>
#include <cstdint>
#include <cstddef>

// ---------- helpers ----------
__device__ __forceinline__ float bf2f(unsigned short u) {
    return __uint_as_float(((unsigned int)u) << 16);
}
__device__ __forceinline__ unsigned short f2bf(float f) {
    unsigned int u = __float_as_uint(f);
    unsigned int r = (u + 0x7fff + ((u >> 16) & 1)) >> 16;
    return (unsigned short)r;
}

using bf16x8 = __attribute__((ext_vector_type(8))) short;
using f32x4  = __attribute__((ext_vector_type(4))) float;
typedef float f32x2 __attribute__((ext_vector_type(2)));

// fp8 (HW format, e4m3 on gfx950) helpers — scale S=64 folded in producer/consumer
#define FP8_SCALE    64.0f
#define FP8_INVSCALE 0.015625f

__device__ __forceinline__ unsigned char f2fp8(float v) {
    int p = __builtin_amdgcn_cvt_pk_fp8_f32(v, v, 0, false);
    return (unsigned char)(p & 0xFF);
}
__device__ __forceinline__ void acc_fp8x8(unsigned lo, unsigned hi, float* a) {
    f32x2 f0 = __builtin_amdgcn_cvt_pk_f32_fp8((int)lo, false);
    f32x2 f1 = __builtin_amdgcn_cvt_pk_f32_fp8((int)lo, true);
    f32x2 f2 = __builtin_amdgcn_cvt_pk_f32_fp8((int)hi, false);
    f32x2 f3 = __builtin_amdgcn_cvt_pk_f32_fp8((int)hi, true);
    a[0] += f0[0]; a[1] += f0[1]; a[2] += f1[0]; a[3] += f1[1];
    a[4] += f2[0]; a[5] += f2[1]; a[6] += f3[0]; a[7] += f3[1];
}

// packed fp32->bf16 (RTNE, same rounding as f2bf) — 1 inst per 2 floats
__device__ __forceinline__ bf16x8 cvt8(float4 a, float4 b) {
    union { unsigned u[4]; bf16x8 v; } r;
    asm("v_cvt_pk_bf16_f32 %0, %1, %2" : "=v"(r.u[0]) : "v"(a.x), "v"(a.y));
    asm("v_cvt_pk_bf16_f32 %0, %1, %2" : "=v"(r.u[1]) : "v"(a.z), "v"(a.w));
    asm("v_cvt_pk_bf16_f32 %0, %1, %2" : "=v"(r.u[2]) : "v"(b.x), "v"(b.y));
    asm("v_cvt_pk_bf16_f32 %0, %1, %2" : "=v"(r.u[3]) : "v"(b.z), "v"(b.w));
    return r.v;
}

// ---------- bucketed CSR build ----------
#define BKT_SHIFT 9
#define BKT_NODES 512
#define BKT_CAP   18432
#define BIN_TILE  4096
#define PAD_G     8                       // degree padding granularity
#define BKT_PADMAX (BKT_NODES * (PAD_G - 1))  // worst-case pad per bucket

// packed entry: (src << 9) | dst_local  (requires n < 2^23)
__global__ __launch_bounds__(256) void bin_kernel(const int* __restrict__ eidx, int E,
                                                  int nb, int ntiles,
                                                  int* __restrict__ gcur,
                                                  unsigned* __restrict__ binned) {
    __shared__ int cnt[256];
    __shared__ int base[256];
    const int tid = threadIdx.x;
    for (int t = blockIdx.x; t < ntiles; t += gridDim.x) {
        cnt[tid] = 0;
        __syncthreads();
        int s[16], d[16];
        unsigned pk[16];  // (b << 16) | rank ; 0xFFFFFFFF = invalid
        #pragma unroll
        for (int j = 0; j < 16; ++j) {
            int e = t * BIN_TILE + j * 256 + tid;
            if (e < E) {
                s[j] = eidx[e];
                d[j] = eidx[E + e];
                int b = d[j] >> BKT_SHIFT;
                int r = atomicAdd(&cnt[b], 1);
                pk[j] = ((unsigned)b << 16) | (unsigned)r;
            } else {
                pk[j] = 0xFFFFFFFFu;
            }
        }
        __syncthreads();
        if (tid < nb) {
            int c = cnt[tid];
            base[tid] = c ? atomicAdd(&gcur[tid], c) : 0;
        }
        __syncthreads();
        #pragma unroll
        for (int j = 0; j < 16; ++j) {
            if (pk[j] != 0xFFFFFFFFu) {
                int b = (int)(pk[j] >> 16);
                int pos = base[b] + (int)(pk[j] & 0xFFFFu);
                if (pos < BKT_CAP)
                    binned[(size_t)b * BKT_CAP + pos] =
                        ((unsigned)s[j] << BKT_SHIFT) | ((unsigned)d[j] & (BKT_NODES - 1));
            }
        }
        __syncthreads();
    }
}

// fused: bucket-base scan (padded worst-case, redundant per block) + per-bucket
// histogram + local scan with degree padding to PAD_G -> rowptr, pdeg (in deg[]),
// dinv, csr_src (pad slots get sentinel src = n -> zeroed feature row).
// Row ends come from deg[node], NOT rowptr[node+1] (bucket regions have gaps).
__global__ __launch_bounds__(256) void csr_build_kernel(const unsigned* __restrict__ binned,
                                                        const int* __restrict__ gcur,
                                                        int* __restrict__ rowptr,
                                                        int* __restrict__ deg,
                                                        float* __restrict__ dinv,
                                                        int* __restrict__ csr_src,
                                                        int nb, int n) {
    __shared__ int cnt[BKT_NODES];
    __shared__ int sbase[256];
    __shared__ int wsum[4];
    const int b = blockIdx.x;
    const int base_node = b << BKT_SHIFT;
    const int tid = threadIdx.x, lane = tid & 63, wave = tid >> 6;

    // bucket-base exclusive scan over padded-worst-case bucket sizes
    int c = (tid < nb) ? (min(gcur[tid], BKT_CAP) + BKT_PADMAX) : 0;
    int inc = c;
    #pragma unroll
    for (int off = 1; off < 64; off <<= 1) {
        int t = __shfl_up(inc, off, 64);
        if (lane >= off) inc += t;
    }
    if (lane == 63) wsum[wave] = inc;
    __syncthreads();
    int wbase = 0;
    #pragma unroll
    for (int w = 0; w < 4; ++w)
        if (w < wave) wbase += wsum[w];
    sbase[tid] = wbase + inc - c;
    __syncthreads();
    const int gb = sbase[b];
    __syncthreads();

    // per-bucket histogram (real counts)
    for (int i = tid; i < BKT_NODES; i += 256) cnt[i] = 0;
    __syncthreads();
    const int m = min(gcur[b], BKT_CAP);
    const unsigned* eb = binned + (size_t)b * BKT_CAP;
    for (int i = tid; i < m; i += 256)
        atomicAdd(&cnt[eb[i] & (BKT_NODES - 1)], 1);
    __syncthreads();

    // local scan over PADDED counts (2 elems/thread) -> rowptr, deg, dinv, cursors
    int c0 = cnt[2 * tid], c1 = cnt[2 * tid + 1];
    int pc0 = (c0 + PAD_G - 1) & ~(PAD_G - 1);
    int pc1 = (c1 + PAD_G - 1) & ~(PAD_G - 1);
    int s = pc0 + pc1;
    int inc2 = s;
    #pragma unroll
    for (int off = 1; off < 64; off <<= 1) {
        int t = __shfl_up(inc2, off, 64);
        if (lane >= off) inc2 += t;
    }
    __syncthreads();  // wsum reuse
    if (lane == 63) wsum[wave] = inc2;
    __syncthreads();
    int wbase2 = 0;
    #pragma unroll
    for (int w = 0; w < 4; ++w)
        if (w < wave) wbase2 += wsum[w];
    int excl = wbase2 + inc2 - s;
    int node0 = base_node + 2 * tid;
    int st0 = gb + excl, st1 = gb + excl + pc0;
    if (node0 < n) {
        rowptr[node0] = st0;
        deg[node0] = pc0;
        dinv[node0] = rsqrtf((float)c0 + 1.0f);
        // pad-slot fill with sentinel (zero-row) src = n
        for (int q = c0; q < pc0; ++q) csr_src[st0 + q] = n;
    }
    if (node0 + 1 < n) {
        rowptr[node0 + 1] = st1;
        deg[node0 + 1] = pc1;
        dinv[node0 + 1] = rsqrtf((float)c1 + 1.0f);
        for (int q = c1; q < pc1; ++q) csr_src[st1 + q] = n;
    }
    __syncthreads();
    cnt[2 * tid] = st0;
    cnt[2 * tid + 1] = st1;
    __syncthreads();

    // fill real entries
    for (int i = tid; i < m; i += 256) {
        unsigned p = eb[i];
        int pos = atomicAdd(&cnt[p & (BKT_NODES - 1)], 1);
        csr_src[pos] = (int)(p >> BKT_SHIFT);
    }
}

// ---------- fallback CSR build (tight rows; deg = true degree) ----------
__global__ __launch_bounds__(256) void hist_kernel(const int* __restrict__ dst, int E,
                                                   int* __restrict__ deg) {
    int i = blockIdx.x * blockDim.x + threadIdx.x;
    int stride = gridDim.x * blockDim.x;
    for (int e = i; e < E; e += stride) atomicAdd(&deg[dst[e]], 1);
}

__global__ __launch_bounds__(256) void fill_kernel(const int* __restrict__ eidx, int E,
                                                   int* __restrict__ cursor,
                                                   int* __restrict__ csr_src) {
    int e = blockIdx.x * blockDim.x + threadIdx.x;
    if (e < E) {
        int s = eidx[e];
        int d = eidx[E + e];
        int pos = atomicAdd(&cursor[d], 1);
        csr_src[pos] = s;
    }
}

__global__ __launch_bounds__(256) void scan_kernel(const int* __restrict__ deg,
                                                   int* __restrict__ rowptr, int n) {
    __shared__ int wsum[4];
    __shared__ int carry_s;
    int tid = threadIdx.x, lane = tid & 63, wave = tid >> 6;
    if (tid == 0) carry_s = 0;
    __syncthreads();
    const int CHUNK = 16;
    const int PER_ITER = 256 * CHUNK;
    for (int base = 0; base < n; base += PER_ITER) {
        int idx0 = base + tid * CHUNK;
        int v[CHUNK];
        int s = 0;
        #pragma unroll
        for (int j = 0; j < CHUNK; ++j) {
            int i = idx0 + j;
            v[j] = (i < n) ? deg[i] : 0;
            s += v[j];
        }
        int inc = s;
        #pragma unroll
        for (int off = 1; off < 64; off <<= 1) {
            int t = __shfl_up(inc, off, 64);
            if (lane >= off) inc += t;
        }
        if (lane == 63) wsum[wave] = inc;
        __syncthreads();
        int wbase = 0;
        #pragma unroll
        for (int w = 0; w < 4; ++w)
            if (w < wave) wbase += wsum[w];
        int total_iter = wsum[0] + wsum[1] + wsum[2] + wsum[3];
        int carry = carry_s;
        __syncthreads();
        if (tid == 0) carry_s = carry + total_iter;
        int run = carry + wbase + (inc - s);
        #pragma unroll
        for (int j = 0; j < CHUNK; ++j) {
            int i = idx0 + j;
            if (i < n) rowptr[i] = run;
            run += v[j];
        }
        __syncthreads();
    }
    if (tid == 0) rowptr[n] = carry_s;
}

__global__ __launch_bounds__(256) void dinv_kernel(const int* __restrict__ deg,
                                                   float* __restrict__ dinv, int n) {
    int i = blockIdx.x * blockDim.x + threadIdx.x;
    if (i < n) dinv[i] = rsqrtf((float)deg[i] + 1.0f);
}

// ---------- weight fragment-pack + sentinel-row zeroing (one launch) ----------
// WF layout: block blk = (k0/32)*(N/16) + f   (512 shorts/block)
//   within block: lane*8 + jj where lane = quad*16 + l16
//   element = W[k0 + quad*8 + jj][f*16 + l16]
// Consumer: bfr = WF + (blk << 9) + lane*8  -> one coalesced 16B load per lane.
__global__ __launch_bounds__(256) void wt_kernel(const float* __restrict__ W1,
                                                 const float* __restrict__ W2,
                                                 unsigned short* __restrict__ W1F,
                                                 unsigned short* __restrict__ W2F,
                                                 unsigned char* __restrict__ hA_sent,
                                                 unsigned char* __restrict__ hB_sent) {
    int i = blockIdx.x * 256 + threadIdx.x;
    const int n1 = 512 * 256;
    if (i < n1) {
        // W1F: K=512, N=256, 16 blocks per k0
        int blk = i >> 9, r = i & 511;
        int lane = r >> 3, jj = r & 7;
        int k0 = (blk >> 4) << 5;
        int f = blk & 15;
        int quad = lane >> 4, l16 = lane & 15;
        int k = k0 + quad * 8 + jj;
        int nn = f * 16 + l16;
        W1F[i] = f2bf(W1[(size_t)k * 256 + nn]);
    } else {
        int j = i - n1;
        if (j < 256 * 128) {
            // W2F: K=256, N=128, 8 blocks per k0
            int blk = j >> 9, r = j & 511;
            int lane = r >> 3, jj = r & 7;
            int k0 = (blk >> 3) << 5;
            int f = blk & 7;
            int quad = lane >> 4, l16 = lane & 15;
            int k = k0 + quad * 8 + jj;
            int nn = f * 16 + l16;
            W2F[j] = f2bf(W2[(size_t)k * 128 + nn]);
        }
    }
    // sentinel zero rows (gather target for CSR pad slots)
    if (blockIdx.x == 0) {
        if (threadIdx.x < 256) hA_sent[threadIdx.x] = 0;
        if (threadIdx.x < 128) hB_sent[threadIdx.x] = 0;
    }
}

// ---------- GEMM1: hs1[M,256](fp8, * dinv * 64) = x[M,512] @ W1 ----------
// 2-phase pipelined, N-split waves: each wave owns a 64(M) x 64(N) tile so each
// B-fragment is reused by 4 A-fragments. A (fp32) staged to LDS via
// global_load_lds (dbuf, XOR-swizzled src+read).
__global__ __launch_bounds__(256, 4) void gemm1_kernel(const float* __restrict__ x,
                                                       const unsigned short* __restrict__ W1F,
                                                       const float* __restrict__ dinv,
                                                       unsigned char* __restrict__ C,
                                                       int M) {
    __shared__ float As[2][4096];  // 2 x (64 rows x 64 floats) = 2 x 16 KB
    const int tid = threadIdx.x;
    const int wave = tid >> 6, lane = tid & 63;
    const int quad = lane >> 4, l16 = lane & 15;
    const int m0 = blockIdx.x * 64;

    // staging sources: unit = wave*4+c covers LDS rows unit*4..unit*4+3;
    // lane l stages dest byte unit*1024 + l*16 (HW: uniform base + lane*16).
    const float* sbase[4];
    #pragma unroll
    for (int c = 0; c < 4; ++c) {
        int row  = (wave * 4 + c) * 4 + (lane >> 4);
        int grow = min(m0 + row, M - 1);
        int scb  = ((lane & 15) << 4) ^ ((row & 7) << 4);  // pre-swizzled col byte
        sbase[c] = x + (size_t)grow * 512 + (scb >> 2);
    }
    // fragment-read swizzle (row = am*16 + l16; am*16 % 8 == 0 -> row&7 == l16&7)
    const int swz = (l16 & 7) << 4;

    // prologue: stage k-step 0 into buf 0
    #pragma unroll
    for (int c = 0; c < 4; ++c)
        __builtin_amdgcn_global_load_lds(sbase[c], &As[0][(wave * 4 + c) * 256], 16, 0, 0);
    __syncthreads();

    f32x4 acc[4][4] = {};  // [am][bn]
    for (int t = 0; t < 8; ++t) {
        const int cur = t & 1;
        if (t < 7) {  // issue next stage BEFORE compute (overlap)
            #pragma unroll
            for (int c = 0; c < 4; ++c)
                __builtin_amdgcn_global_load_lds(sbase[c] + (t + 1) * 64,
                                                 &As[cur ^ 1][(wave * 4 + c) * 256], 16, 0, 0);
        }
        const char* ab = reinterpret_cast<const char*>(&As[cur][0]);
        #pragma unroll
        for (int ks = 0; ks < 2; ++ks) {
            const int cb = (ks << 7) + (quad << 5);
            // 4 B-fragments for this wave's N-slice (cols wave*64 .. +63)
            const unsigned short* wp =
                W1F + (((((t << 1) + ks) << 4) + (wave << 2)) << 9) + lane * 8;
            bf16x8 bfr0 = *reinterpret_cast<const bf16x8*>(wp);
            bf16x8 bfr1 = *reinterpret_cast<const bf16x8*>(wp + 512);
            bf16x8 bfr2 = *reinterpret_cast<const bf16x8*>(wp + 1024);
            bf16x8 bfr3 = *reinterpret_cast<const bf16x8*>(wp + 1536);
            #pragma unroll
            for (int am = 0; am < 4; ++am) {
                const char* rp = ab + ((am * 16 + l16) << 8);
                float4 a0 = *reinterpret_cast<const float4*>(rp + (cb ^ swz));
                float4 a1 = *reinterpret_cast<const float4*>(rp + ((cb + 16) ^ swz));
                bf16x8 af = cvt8(a0, a1);
                acc[am][0] = __builtin_amdgcn_mfma_f32_16x16x32_bf16(af, bfr0, acc[am][0], 0, 0, 0);
                acc[am][1] = __builtin_amdgcn_mfma_f32_16x16x32_bf16(af, bfr1, acc[am][1], 0, 0, 0);
                acc[am][2] = __builtin_amdgcn_mfma_f32_16x16x32_bf16(af, bfr2, acc[am][2], 0, 0, 0);
                acc[am][3] = __builtin_amdgcn_mfma_f32_16x16x32_bf16(af, bfr3, acc[am][3], 0, 0, 0);
            }
        }
        __syncthreads();  // drains in-flight stage + protects buf reuse
    }

    #pragma unroll
    for (int am = 0; am < 4; ++am) {
        #pragma unroll
        for (int rr = 0; rr < 4; ++rr) {
            int row = m0 + am * 16 + quad * 4 + rr;
            if (row < M) {
                float dv = dinv[row] * FP8_SCALE;
                #pragma unroll
                for (int bn = 0; bn < 4; ++bn)
                    C[(size_t)row * 256 + wave * 64 + bn * 16 + l16] =
                        f2fp8(acc[am][bn][rr] * dv);
            }
        }
    }
}

// ---------- fused agg1 + gemm2 ----------
__device__ __forceinline__ int a2_idx(int row, int col) {
    int byte = (row << 9) + (col << 1);
    byte ^= (row & 7) << 4;
    return byte >> 1;
}

__global__ __launch_bounds__(256, 4) void agg1_gemm2_kernel(const unsigned char* __restrict__ hs1,
                                                            const float* __restrict__ dinv,
                                                            const int* __restrict__ rowptr,
                                                            const int* __restrict__ deg,
                                                            const int* __restrict__ csr_src,
                                                            const float* __restrict__ b1,
                                                            const unsigned short* __restrict__ W2F,
                                                            unsigned char* __restrict__ hs2,
                                                            int n) {
    __shared__ __align__(16) short As2[64 * 256];  // 32 KB exact
    const int tid = threadIdx.x;
    const int m0 = blockIdx.x * 64;

    // ---- phase 1: gather (32 lanes/node, 8 feats/lane, fp8 rows 256 B) ----
    // 16-deep main loop: 2x outstanding loads per wave vs round 6 (regime probe:
    // latency-bound -> faster; L2-line-rate-bound -> flat). uint2 keeps per-lane
    // state at ~85 VGPR (s[16]+w[16]x2+a[8]) — no spill under the 128 cap.
    {
        const int lane = tid & 31;
        const int sub = tid >> 5;  // 0..7
        const unsigned char* tab = hs1 + (size_t)lane * 8;
        float4 blo = *(reinterpret_cast<const float4*>(b1) + lane * 2);
        float4 bhi = *(reinterpret_cast<const float4*>(b1) + lane * 2 + 1);
        float bvals[8] = {blo.x, blo.y, blo.z, blo.w, bhi.x, bhi.y, bhi.z, bhi.w};
        for (int g = 0; g < 8; ++g) {
            int row = g * 8 + sub;
            int node = m0 + row;
            float h[8] = {};
            if (node < n) {
                float a[8] = {};
                uint2 v0 = *reinterpret_cast<const uint2*>(tab + (size_t)node * 256);
                acc_fp8x8(v0.x, v0.y, a);  // self term
                int e0 = rowptr[node], e1 = e0 + deg[node];
                int p = e0;
                for (; p + 16 <= e1; p += 16) {
                    int s[16];
                    #pragma unroll
                    for (int u = 0; u < 16; ++u) s[u] = csr_src[p + u];
                    uint2 w[16];
                    #pragma unroll
                    for (int u = 0; u < 16; ++u)
                        w[u] = *reinterpret_cast<const uint2*>(tab + (size_t)s[u] * 256);
                    #pragma unroll
                    for (int u = 0; u < 16; ++u)
                        acc_fp8x8(w[u].x, w[u].y, a);
                }
                if (p + 8 <= e1) {
                    int s[8];
                    #pragma unroll
                    for (int u = 0; u < 8; ++u) s[u] = csr_src[p + u];
                    uint2 w[8];
                    #pragma unroll
                    for (int u = 0; u < 8; ++u)
                        w[u] = *reinterpret_cast<const uint2*>(tab + (size_t)s[u] * 256);
                    #pragma unroll
                    for (int u = 0; u < 8; ++u)
                        acc_fp8x8(w[u].x, w[u].y, a);
                    p += 8;
                }
                for (; p < e1; ++p) {  // only on fallback (unpadded) CSR
                    int s = csr_src[p];
                    uint2 w = *reinterpret_cast<const uint2*>(tab + (size_t)s * 256);
                    acc_fp8x8(w.x, w.y, a);
                }
                float dv = dinv[node] * FP8_INVSCALE;
                #pragma unroll
                for (int j = 0; j < 8; ++j)
                    h[j] = fmaxf(fmaf(a[j], dv, bvals[j]), 0.f);
            }
            bf16x8 o;
            #pragma unroll
            for (int j = 0; j < 8; ++j) o[j] = (short)f2bf(h[j]);
            *reinterpret_cast<bf16x8*>(&As2[a2_idx(row, lane * 8)]) = o;
        }
    }
    __syncthreads();

    // ---- phase 2: MFMA K=256, N=128, B direct from W2F, no barriers ----
    const int wave = tid >> 6, lane = tid & 63;
    const int quad = lane >> 4, l16 = lane & 15;
    const int arow = wave * 16 + l16;
    f32x4 acc[2][4] = {};
    #pragma unroll
    for (int k0 = 0; k0 < 256; k0 += 32) {
        bf16x8 af = *reinterpret_cast<const bf16x8*>(&As2[a2_idx(arow, k0 + quad * 8)]);
        #pragma unroll
        for (int i = 0; i < 2; ++i) {
            #pragma unroll
            for (int ct = 0; ct < 4; ++ct) {
                bf16x8 bfr = *reinterpret_cast<const bf16x8*>(
                    W2F + ((((k0 >> 5) << 3) + i * 4 + ct) << 9) + lane * 8);
                acc[i][ct] = __builtin_amdgcn_mfma_f32_16x16x32_bf16(af, bfr, acc[i][ct], 0, 0, 0);
            }
        }
    }
    #pragma unroll
    for (int r = 0; r < 4; ++r) {
        int row = m0 + wave * 16 + quad * 4 + r;
        if (row < n) {
            float dv = dinv[row] * FP8_SCALE;
            #pragma unroll
            for (int i = 0; i < 2; ++i)
                #pragma unroll
                for (int ct = 0; ct < 4; ++ct)
                    hs2[(size_t)row * 128 + i * 64 + ct * 16 + l16] =
                        f2fp8(acc[i][ct][r] * dv);
        }
    }
}

// ---------- agg layer 2 + fused head (fp8 hs2, rows 128 B, 16 lanes/node) ----------
__global__ __launch_bounds__(256) void agg2_head_kernel(const unsigned char* __restrict__ hs,
                                                        const float* __restrict__ dinv,
                                                        const int* __restrict__ rowptr,
                                                        const int* __restrict__ deg,
                                                        const int* __restrict__ csr_src,
                                                        const float* __restrict__ bias,
                                                        const float* __restrict__ Wl,
                                                        const float* __restrict__ bl,
                                                        float* __restrict__ out, int n) {
    constexpr int LANES = 16, H = 128, NPB = 16;
    int sub = threadIdx.x / LANES;
    int lane = threadIdx.x % LANES;
    int node = blockIdx.x * NPB + sub;
    if (node >= n) return;
    const unsigned char* tab = hs + (size_t)lane * 8;
    float a[8] = {};
    uint2 v0 = *reinterpret_cast<const uint2*>(tab + (size_t)node * H);
    acc_fp8x8(v0.x, v0.y, a);  // self term
    int e0 = rowptr[node], e1 = e0 + deg[node];
    int p = e0;
    for (; p + 8 <= e1; p += 8) {
        int s[8];
        #pragma unroll
        for (int u = 0; u < 8; ++u) s[u] = csr_src[p + u];
        uint2 w[8];
        #pragma unroll
        for (int u = 0; u < 8; ++u)
            w[u] = *reinterpret_cast<const uint2*>(tab + (size_t)s[u] * H);
        #pragma unroll
        for (int u = 0; u < 8; ++u)
            acc_fp8x8(w[u].x, w[u].y, a);
    }
    for (; p < e1; ++p) {  // only on fallback CSR
        int s = csr_src[p];
        uint2 w = *reinterpret_cast<const uint2*>(tab + (size_t)s * H);
        acc_fp8x8(w.x, w.y, a);
    }
    float dv = dinv[node] * FP8_INVSCALE;
    float4 blo = *(reinterpret_cast<const float4*>(bias) + lane * 2);
    float4 bhi = *(reinterpret_cast<const float4*>(bias) + lane * 2 + 1);
    float bvals[8] = {blo.x, blo.y, blo.z, blo.w, bhi.x, bhi.y, bhi.z, bhi.w};
    float h[8];
    #pragma unroll
    for (int j = 0; j < 8; ++j)
        h[j] = fmaxf(fmaf(a[j], dv, bvals[j]), 0.f);
    float p0 = 0.f, p1 = 0.f, p2 = 0.f, p3 = 0.f;
    #pragma unroll
    for (int j = 0; j < 8; ++j) {
        float4 w = *reinterpret_cast<const float4*>(Wl + (size_t)(lane * 8 + j) * 4);
        p0 = fmaf(h[j], w.x, p0); p1 = fmaf(h[j], w.y, p1);
        p2 = fmaf(h[j], w.z, p2); p3 = fmaf(h[j], w.w, p3);
    }
    #pragma unroll
    for (int m = 1; m < 16; m <<= 1) {
        p0 += __shfl_xor(p0, m, 16);
        p1 += __shfl_xor(p1, m, 16);
        p2 += __shfl_xor(p2, m, 16);
        p3 += __shfl_xor(p3, m, 16);
    }
    if (lane == 0) {
        p0 += bl[0]; p1 += bl[1]; p2 += bl[2]; p3 += bl[3];
        float mx = fmaxf(fmaxf(p0, p1), fmaxf(p2, p3));
        float s = __expf(p0 - mx) + __expf(p1 - mx) + __expf(p2 - mx) + __expf(p3 - mx);
        float lse = mx + __logf(s);
        *(reinterpret_cast<float4*>(out) + node) = make_float4(p0 - lse, p1 - lse, p2 - lse, p3 - lse);
    }
}

// ---------- launch ----------
extern "C" void kernel_launch(void* const* d_in, const int* in_sizes, int n_in,
                              void* d_out, int out_size, void* d_ws, size_t ws_size,
                              hipStream_t stream) {
    const float* x  = (const float*)d_in[0];
    const int* eidx = (const int*)d_in[1];
    const float* W1 = (const float*)d_in[2];
    const float* b1 = (const float*)d_in[3];
    const float* W2 = (const float*)d_in[4];
    const float* b2 = (const float*)d_in[5];
    const float* Wl = (const float*)d_in[6];
    const float* bl = (const float*)d_in[7];
    float* out = (float*)d_out;

    const int n = in_sizes[0] / 512;
    const int E = in_sizes[1] / 2;
    const int nb = (n + BKT_NODES - 1) >> BKT_SHIFT;  // 196 for n=100000

    char* ws = (char*)d_ws;
    size_t off = 0;
    auto alloc = [&](size_t bytes) -> void* {
        void* p = ws + off;
        off += (bytes + 255) & ~(size_t)255;
        return p;
    };
    unsigned char*  hA  = (unsigned char*)alloc((size_t)(n + 1) * 256);  // hs1 fp8 + zero row
    unsigned char*  hB  = (unsigned char*)alloc((size_t)(n + 1) * 128);  // hs2 fp8 + zero row
    unsigned short* W1F = (unsigned short*)alloc((size_t)256 * 512 * 2);
    unsigned short* W2F = (unsigned short*)alloc((size_t)128 * 256 * 2);
    int* deg     = (int*)alloc((size_t)n * 4);
    int* rowptr  = (int*)alloc(((size_t)n + 1) * 4);
    int* cursor  = (int*)alloc((size_t)n * 4);
    float* dinv  = (float*)alloc((size_t)n * 4);
    int* csr_src = (int*)alloc(((size_t)E + (size_t)nb * BKT_PADMAX + 64) * 4);
    int* gcur    = (int*)alloc((size_t)nb * 4);
    size_t need_binned = off + (size_t)nb * BKT_CAP * 4 + 256;
    unsigned* binned = (unsigned*)alloc((size_t)nb * BKT_CAP * 4);

    if (need_binned <= ws_size && nb <= 256 && n < (1 << 23)) {
        hipMemsetAsync(gcur, 0, (size_t)nb * 4, stream);
        int ntiles = (E + BIN_TILE - 1) / BIN_TILE;
        int bgrid = ntiles < 1024 ? ntiles : 1024;
        bin_kernel<<<dim3(bgrid), dim3(256), 0, stream>>>(eidx, E, nb, ntiles, gcur, binned);
        csr_build_kernel<<<dim3(nb), dim3(256), 0, stream>>>(binned, gcur, rowptr, deg, dinv,
                                                             csr_src, nb, n);
    } else {
        hipMemsetAsync(deg, 0, (size_t)n * 4, stream);
        hist_kernel<<<dim3(1024), dim3(256), 0, stream>>>(eidx + E, E, deg);
        scan_kernel<<<dim3(1), dim3(256), 0, stream>>>(deg, rowptr, n);
        dinv_kernel<<<dim3((n + 255) / 256), dim3(256), 0, stream>>>(deg, dinv, n);
        hipMemcpyAsync(cursor, rowptr, (size_t)n * 4, hipMemcpyDeviceToDevice, stream);
        fill_kernel<<<dim3((E + 255) / 256), dim3(256), 0, stream>>>(eidx, E, cursor, csr_src);
    }

    // Weight fragment-pack + sentinel-row zeroing (single launch)
    wt_kernel<<<dim3((512 * 256 + 256 * 128 + 255) / 256), dim3(256), 0, stream>>>(
        W1, W2, W1F, W2F, hA + (size_t)n * 256, hB + (size_t)n * 128);

    const int mblocks = (n + 63) / 64;

    // Layer 1 GEMM: hs1 = fp8((x@W1)*dinv*64)   (2-phase pipelined, N-split waves)
    gemm1_kernel<<<dim3(mblocks), dim3(256), 0, stream>>>(x, W1F, dinv, hA, n);

    // Fused agg1 + gemm2: hs2 = fp8((relu(agg(hs1))@W2)*dinv*64)
    agg1_gemm2_kernel<<<dim3(mblocks), dim3(256), 0, stream>>>(
        hA, dinv, rowptr, deg, csr_src, b1, W2F, hB, n);

    // agg2 + head fused (fp8 gather)
    agg2_head_kernel<<<dim3((n + 15) / 16), dim3(256), 0, stream>>>(
        hB, dinv, rowptr, deg, csr_src, b2, Wl, bl, out, n);
}

// Round 9
// 603.387 us; speedup vs baseline: 1.3466x; 1.0017x over previous
//
#include <hip/hip_runtime.h>
#include <hip/hip_bf16.h>
#include <cstdint>
#include <cstddef>

// ---------- helpers ----------
__device__ __forceinline__ float bf2f(unsigned short u) {
    return __uint_as_float(((unsigned int)u) << 16);
}
__device__ __forceinline__ unsigned short f2bf(float f) {
    unsigned int u = __float_as_uint(f);
    unsigned int r = (u + 0x7fff + ((u >> 16) & 1)) >> 16;
    return (unsigned short)r;
}

using bf16x8 = __attribute__((ext_vector_type(8))) short;
using f32x4  = __attribute__((ext_vector_type(4))) float;
typedef float f32x2 __attribute__((ext_vector_type(2)));

// fp8 (HW format, e4m3 on gfx950) helpers — scale S=64 folded in producer/consumer
#define FP8_SCALE    64.0f
#define FP8_INVSCALE 0.015625f

__device__ __forceinline__ unsigned char f2fp8(float v) {
    int p = __builtin_amdgcn_cvt_pk_fp8_f32(v, v, 0, false);
    return (unsigned char)(p & 0xFF);
}
__device__ __forceinline__ void acc_fp8x8(unsigned lo, unsigned hi, float* a) {
    f32x2 f0 = __builtin_amdgcn_cvt_pk_f32_fp8((int)lo, false);
    f32x2 f1 = __builtin_amdgcn_cvt_pk_f32_fp8((int)lo, true);
    f32x2 f2 = __builtin_amdgcn_cvt_pk_f32_fp8((int)hi, false);
    f32x2 f3 = __builtin_amdgcn_cvt_pk_f32_fp8((int)hi, true);
    a[0] += f0[0]; a[1] += f0[1]; a[2] += f1[0]; a[3] += f1[1];
    a[4] += f2[0]; a[5] += f2[1]; a[6] += f3[0]; a[7] += f3[1];
}

// packed fp32->bf16 (RTNE, same rounding as f2bf) — 1 inst per 2 floats
__device__ __forceinline__ bf16x8 cvt8(float4 a, float4 b) {
    union { unsigned u[4]; bf16x8 v; } r;
    asm("v_cvt_pk_bf16_f32 %0, %1, %2" : "=v"(r.u[0]) : "v"(a.x), "v"(a.y));
    asm("v_cvt_pk_bf16_f32 %0, %1, %2" : "=v"(r.u[1]) : "v"(a.z), "v"(a.w));
    asm("v_cvt_pk_bf16_f32 %0, %1, %2" : "=v"(r.u[2]) : "v"(b.x), "v"(b.y));
    asm("v_cvt_pk_bf16_f32 %0, %1, %2" : "=v"(r.u[3]) : "v"(b.z), "v"(b.w));
    return r.v;
}

// ---------- bucketed CSR build ----------
#define BKT_SHIFT 9
#define BKT_NODES 512
#define BKT_CAP   18432
#define BIN_TILE  4096
#define PAD_G     8                       // degree padding granularity
#define BKT_PADMAX (BKT_NODES * (PAD_G - 1))  // worst-case pad per bucket

// packed entry: (src << 9) | dst_local  (requires n < 2^23)
__global__ __launch_bounds__(256) void bin_kernel(const int* __restrict__ eidx, int E,
                                                  int nb, int ntiles,
                                                  int* __restrict__ gcur,
                                                  unsigned* __restrict__ binned) {
    __shared__ int cnt[256];
    __shared__ int base[256];
    const int tid = threadIdx.x;
    for (int t = blockIdx.x; t < ntiles; t += gridDim.x) {
        cnt[tid] = 0;
        __syncthreads();
        int s[16], d[16];
        unsigned pk[16];  // (b << 16) | rank ; 0xFFFFFFFF = invalid
        #pragma unroll
        for (int j = 0; j < 16; ++j) {
            int e = t * BIN_TILE + j * 256 + tid;
            if (e < E) {
                s[j] = eidx[e];
                d[j] = eidx[E + e];
                int b = d[j] >> BKT_SHIFT;
                int r = atomicAdd(&cnt[b], 1);
                pk[j] = ((unsigned)b << 16) | (unsigned)r;
            } else {
                pk[j] = 0xFFFFFFFFu;
            }
        }
        __syncthreads();
        if (tid < nb) {
            int c = cnt[tid];
            base[tid] = c ? atomicAdd(&gcur[tid], c) : 0;
        }
        __syncthreads();
        #pragma unroll
        for (int j = 0; j < 16; ++j) {
            if (pk[j] != 0xFFFFFFFFu) {
                int b = (int)(pk[j] >> 16);
                int pos = base[b] + (int)(pk[j] & 0xFFFFu);
                if (pos < BKT_CAP)
                    binned[(size_t)b * BKT_CAP + pos] =
                        ((unsigned)s[j] << BKT_SHIFT) | ((unsigned)d[j] & (BKT_NODES - 1));
            }
        }
        __syncthreads();
    }
}

// fused: bucket-base scan (padded worst-case, redundant per block) + per-bucket
// histogram + local scan with degree padding to PAD_G -> rowptr, pdeg (in deg[]),
// dinv, csr_src (pad slots get sentinel src = n -> zeroed feature row).
// Row ends come from deg[node], NOT rowptr[node+1] (bucket regions have gaps).
__global__ __launch_bounds__(256) void csr_build_kernel(const unsigned* __restrict__ binned,
                                                        const int* __restrict__ gcur,
                                                        int* __restrict__ rowptr,
                                                        int* __restrict__ deg,
                                                        float* __restrict__ dinv,
                                                        int* __restrict__ csr_src,
                                                        int nb, int n) {
    __shared__ int cnt[BKT_NODES];
    __shared__ int sbase[256];
    __shared__ int wsum[4];
    const int b = blockIdx.x;
    const int base_node = b << BKT_SHIFT;
    const int tid = threadIdx.x, lane = tid & 63, wave = tid >> 6;

    // bucket-base exclusive scan over padded-worst-case bucket sizes
    int c = (tid < nb) ? (min(gcur[tid], BKT_CAP) + BKT_PADMAX) : 0;
    int inc = c;
    #pragma unroll
    for (int off = 1; off < 64; off <<= 1) {
        int t = __shfl_up(inc, off, 64);
        if (lane >= off) inc += t;
    }
    if (lane == 63) wsum[wave] = inc;
    __syncthreads();
    int wbase = 0;
    #pragma unroll
    for (int w = 0; w < 4; ++w)
        if (w < wave) wbase += wsum[w];
    sbase[tid] = wbase + inc - c;
    __syncthreads();
    const int gb = sbase[b];
    __syncthreads();

    // per-bucket histogram (real counts)
    for (int i = tid; i < BKT_NODES; i += 256) cnt[i] = 0;
    __syncthreads();
    const int m = min(gcur[b], BKT_CAP);
    const unsigned* eb = binned + (size_t)b * BKT_CAP;
    for (int i = tid; i < m; i += 256)
        atomicAdd(&cnt[eb[i] & (BKT_NODES - 1)], 1);
    __syncthreads();

    // local scan over PADDED counts (2 elems/thread) -> rowptr, deg, dinv, cursors
    int c0 = cnt[2 * tid], c1 = cnt[2 * tid + 1];
    int pc0 = (c0 + PAD_G - 1) & ~(PAD_G - 1);
    int pc1 = (c1 + PAD_G - 1) & ~(PAD_G - 1);
    int s = pc0 + pc1;
    int inc2 = s;
    #pragma unroll
    for (int off = 1; off < 64; off <<= 1) {
        int t = __shfl_up(inc2, off, 64);
        if (lane >= off) inc2 += t;
    }
    __syncthreads();  // wsum reuse
    if (lane == 63) wsum[wave] = inc2;
    __syncthreads();
    int wbase2 = 0;
    #pragma unroll
    for (int w = 0; w < 4; ++w)
        if (w < wave) wbase2 += wsum[w];
    int excl = wbase2 + inc2 - s;
    int node0 = base_node + 2 * tid;
    int st0 = gb + excl, st1 = gb + excl + pc0;
    if (node0 < n) {
        rowptr[node0] = st0;
        deg[node0] = pc0;
        dinv[node0] = rsqrtf((float)c0 + 1.0f);
        // pad-slot fill with sentinel (zero-row) src = n
        for (int q = c0; q < pc0; ++q) csr_src[st0 + q] = n;
    }
    if (node0 + 1 < n) {
        rowptr[node0 + 1] = st1;
        deg[node0 + 1] = pc1;
        dinv[node0 + 1] = rsqrtf((float)c1 + 1.0f);
        for (int q = c1; q < pc1; ++q) csr_src[st1 + q] = n;
    }
    __syncthreads();
    cnt[2 * tid] = st0;
    cnt[2 * tid + 1] = st1;
    __syncthreads();

    // fill real entries
    for (int i = tid; i < m; i += 256) {
        unsigned p = eb[i];
        int pos = atomicAdd(&cnt[p & (BKT_NODES - 1)], 1);
        csr_src[pos] = (int)(p >> BKT_SHIFT);
    }
}

// ---------- fallback CSR build (tight rows; deg = true degree) ----------
__global__ __launch_bounds__(256) void hist_kernel(const int* __restrict__ dst, int E,
                                                   int* __restrict__ deg) {
    int i = blockIdx.x * blockDim.x + threadIdx.x;
    int stride = gridDim.x * blockDim.x;
    for (int e = i; e < E; e += stride) atomicAdd(&deg[dst[e]], 1);
}

__global__ __launch_bounds__(256) void fill_kernel(const int* __restrict__ eidx, int E,
                                                   int* __restrict__ cursor,
                                                   int* __restrict__ csr_src) {
    int e = blockIdx.x * blockDim.x + threadIdx.x;
    if (e < E) {
        int s = eidx[e];
        int d = eidx[E + e];
        int pos = atomicAdd(&cursor[d], 1);
        csr_src[pos] = s;
    }
}

__global__ __launch_bounds__(256) void scan_kernel(const int* __restrict__ deg,
                                                   int* __restrict__ rowptr, int n) {
    __shared__ int wsum[4];
    __shared__ int carry_s;
    int tid = threadIdx.x, lane = tid & 63, wave = tid >> 6;
    if (tid == 0) carry_s = 0;
    __syncthreads();
    const int CHUNK = 16;
    const int PER_ITER = 256 * CHUNK;
    for (int base = 0; base < n; base += PER_ITER) {
        int idx0 = base + tid * CHUNK;
        int v[CHUNK];
        int s = 0;
        #pragma unroll
        for (int j = 0; j < CHUNK; ++j) {
            int i = idx0 + j;
            v[j] = (i < n) ? deg[i] : 0;
            s += v[j];
        }
        int inc = s;
        #pragma unroll
        for (int off = 1; off < 64; off <<= 1) {
            int t = __shfl_up(inc, off, 64);
            if (lane >= off) inc += t;
        }
        if (lane == 63) wsum[wave] = inc;
        __syncthreads();
        int wbase = 0;
        #pragma unroll
        for (int w = 0; w < 4; ++w)
            if (w < wave) wbase += wsum[w];
        int total_iter = wsum[0] + wsum[1] + wsum[2] + wsum[3];
        int carry = carry_s;
        __syncthreads();
        if (tid == 0) carry_s = carry + total_iter;
        int run = carry + wbase + (inc - s);
        #pragma unroll
        for (int j = 0; j < CHUNK; ++j) {
            int i = idx0 + j;
            if (i < n) rowptr[i] = run;
            run += v[j];
        }
        __syncthreads();
    }
    if (tid == 0) rowptr[n] = carry_s;
}

__global__ __launch_bounds__(256) void dinv_kernel(const int* __restrict__ deg,
                                                   float* __restrict__ dinv, int n) {
    int i = blockIdx.x * blockDim.x + threadIdx.x;
    if (i < n) dinv[i] = rsqrtf((float)deg[i] + 1.0f);
}

// ---------- weight fragment-pack + sentinel-row zeroing (one launch) ----------
// WF layout: block blk = (k0/32)*(N/16) + f   (512 shorts/block)
//   within block: lane*8 + jj where lane = quad*16 + l16
//   element = W[k0 + quad*8 + jj][f*16 + l16]
// Consumer: bfr = WF + (blk << 9) + lane*8  -> one coalesced 16B load per lane.
__global__ __launch_bounds__(256) void wt_kernel(const float* __restrict__ W1,
                                                 const float* __restrict__ W2,
                                                 unsigned short* __restrict__ W1F,
                                                 unsigned short* __restrict__ W2F,
                                                 unsigned char* __restrict__ hA_sent,
                                                 unsigned char* __restrict__ hB_sent) {
    int i = blockIdx.x * 256 + threadIdx.x;
    const int n1 = 512 * 256;
    if (i < n1) {
        // W1F: K=512, N=256, 16 blocks per k0
        int blk = i >> 9, r = i & 511;
        int lane = r >> 3, jj = r & 7;
        int k0 = (blk >> 4) << 5;
        int f = blk & 15;
        int quad = lane >> 4, l16 = lane & 15;
        int k = k0 + quad * 8 + jj;
        int nn = f * 16 + l16;
        W1F[i] = f2bf(W1[(size_t)k * 256 + nn]);
    } else {
        int j = i - n1;
        if (j < 256 * 128) {
            // W2F: K=256, N=128, 8 blocks per k0
            int blk = j >> 9, r = j & 511;
            int lane = r >> 3, jj = r & 7;
            int k0 = (blk >> 3) << 5;
            int f = blk & 7;
            int quad = lane >> 4, l16 = lane & 15;
            int k = k0 + quad * 8 + jj;
            int nn = f * 16 + l16;
            W2F[j] = f2bf(W2[(size_t)k * 128 + nn]);
        }
    }
    // sentinel zero rows (gather target for CSR pad slots)
    if (blockIdx.x == 0) {
        if (threadIdx.x < 256) hA_sent[threadIdx.x] = 0;
        if (threadIdx.x < 128) hB_sent[threadIdx.x] = 0;
    }
}

// ---------- GEMM1: hs1[M,256](fp8, * dinv * 64) = x[M,512] @ W1 ----------
// 3-buffer counted-vmcnt pipeline (T4): 2 stages in flight across raw s_barrier,
// s_waitcnt vmcnt(4) per step (never 0 in steady state) — HBM latency of the
// next-next stage hides under this step's MFMA. N-split waves (64x64 per wave).
// Buffer safety: iter t writes buf[(t+2)%3], reads buf[t%3]; reads of
// buf[(t+2)%3] completed (lgkmcnt) before iter t-1's barrier.
__global__ __launch_bounds__(256, 3) void gemm1_kernel(const float* __restrict__ x,
                                                       const unsigned short* __restrict__ W1F,
                                                       const float* __restrict__ dinv,
                                                       unsigned char* __restrict__ C,
                                                       int M) {
    __shared__ float As[3][4096];  // 3 x (64 rows x 64 floats) = 48 KB
    const int tid = threadIdx.x;
    const int wave = tid >> 6, lane = tid & 63;
    const int quad = lane >> 4, l16 = lane & 15;
    const int m0 = blockIdx.x * 64;

    // staging sources: unit = wave*4+c covers LDS rows unit*4..unit*4+3;
    // lane l stages dest byte unit*1024 + l*16 (HW: uniform base + lane*16).
    const float* sbase[4];
    #pragma unroll
    for (int c = 0; c < 4; ++c) {
        int row  = (wave * 4 + c) * 4 + (lane >> 4);
        int grow = min(m0 + row, M - 1);
        int scb  = ((lane & 15) << 4) ^ ((row & 7) << 4);  // pre-swizzled col byte
        sbase[c] = x + (size_t)grow * 512 + (scb >> 2);
    }
    // fragment-read swizzle (row = am*16 + l16; am*16 % 8 == 0 -> row&7 == l16&7)
    const int swz = (l16 & 7) << 4;

    // prologue: stage t=0 -> buf0, t=1 -> buf1 (8 loads in flight/thread)
    #pragma unroll
    for (int c = 0; c < 4; ++c)
        __builtin_amdgcn_global_load_lds(sbase[c], &As[0][(wave * 4 + c) * 256], 16, 0, 0);
    #pragma unroll
    for (int c = 0; c < 4; ++c)
        __builtin_amdgcn_global_load_lds(sbase[c] + 64, &As[1][(wave * 4 + c) * 256], 16, 0, 0);
    asm volatile("s_waitcnt vmcnt(4)" ::: "memory");  // t=0 landed; t=1 in flight
    __builtin_amdgcn_s_barrier();

    f32x4 acc[4][4] = {};  // [am][bn]
    #pragma unroll
    for (int t = 0; t < 8; ++t) {
        const int cur = t % 3;
        if (t < 6) {  // issue stage t+2 (outstanding -> 8)
            const int nxt = (t + 2) % 3;
            #pragma unroll
            for (int c = 0; c < 4; ++c)
                __builtin_amdgcn_global_load_lds(sbase[c] + (t + 2) * 64,
                                                 &As[nxt][(wave * 4 + c) * 256], 16, 0, 0);
        }
        const char* ab = reinterpret_cast<const char*>(&As[cur][0]);
        #pragma unroll
        for (int ks = 0; ks < 2; ++ks) {
            const int cb = (ks << 7) + (quad << 5);
            // 4 B-fragments for this wave's N-slice (cols wave*64 .. +63)
            const unsigned short* wp =
                W1F + (((((t << 1) + ks) << 4) + (wave << 2)) << 9) + lane * 8;
            bf16x8 bfr0 = *reinterpret_cast<const bf16x8*>(wp);
            bf16x8 bfr1 = *reinterpret_cast<const bf16x8*>(wp + 512);
            bf16x8 bfr2 = *reinterpret_cast<const bf16x8*>(wp + 1024);
            bf16x8 bfr3 = *reinterpret_cast<const bf16x8*>(wp + 1536);
            #pragma unroll
            for (int am = 0; am < 4; ++am) {
                const char* rp = ab + ((am * 16 + l16) << 8);
                float4 a0 = *reinterpret_cast<const float4*>(rp + (cb ^ swz));
                float4 a1 = *reinterpret_cast<const float4*>(rp + ((cb + 16) ^ swz));
                bf16x8 af = cvt8(a0, a1);
                acc[am][0] = __builtin_amdgcn_mfma_f32_16x16x32_bf16(af, bfr0, acc[am][0], 0, 0, 0);
                acc[am][1] = __builtin_amdgcn_mfma_f32_16x16x32_bf16(af, bfr1, acc[am][1], 0, 0, 0);
                acc[am][2] = __builtin_amdgcn_mfma_f32_16x16x32_bf16(af, bfr2, acc[am][2], 0, 0, 0);
                acc[am][3] = __builtin_amdgcn_mfma_f32_16x16x32_bf16(af, bfr3, acc[am][3], 0, 0, 0);
            }
        }
        if (t < 7) {
            // wait until only stage t+2's 4 loads remain -> stage t+1 landed
            if (t < 6) asm volatile("s_waitcnt vmcnt(4)" ::: "memory");
            else       asm volatile("s_waitcnt vmcnt(0)" ::: "memory");
            __builtin_amdgcn_s_barrier();
        }
    }

    #pragma unroll
    for (int am = 0; am < 4; ++am) {
        #pragma unroll
        for (int rr = 0; rr < 4; ++rr) {
            int row = m0 + am * 16 + quad * 4 + rr;
            if (row < M) {
                float dv = dinv[row] * FP8_SCALE;
                #pragma unroll
                for (int bn = 0; bn < 4; ++bn)
                    C[(size_t)row * 256 + wave * 64 + bn * 16 + l16] =
                        f2fp8(acc[am][bn][rr] * dv);
            }
        }
    }
}

// ---------- fused agg1 + gemm2 ----------
__device__ __forceinline__ int a2_idx(int row, int col) {
    int byte = (row << 9) + (col << 1);
    byte ^= (row & 7) << 4;
    return byte >> 1;
}

__global__ __launch_bounds__(256, 4) void agg1_gemm2_kernel(const unsigned char* __restrict__ hs1,
                                                            const float* __restrict__ dinv,
                                                            const int* __restrict__ rowptr,
                                                            const int* __restrict__ deg,
                                                            const int* __restrict__ csr_src,
                                                            const float* __restrict__ b1,
                                                            const unsigned short* __restrict__ W2F,
                                                            unsigned char* __restrict__ hs2,
                                                            int n) {
    __shared__ __align__(16) short As2[64 * 256];  // 32 KB exact
    const int tid = threadIdx.x;
    const int m0 = blockIdx.x * 64;

    // ---- phase 1: gather (32 lanes/node, 8 feats/lane, fp8 rows 256 B) ----
    // 16-deep main loop for latency overlap (round-8 measured: -7% vs 8-deep).
    {
        const int lane = tid & 31;
        const int sub = tid >> 5;  // 0..7
        const unsigned char* tab = hs1 + (size_t)lane * 8;
        float4 blo = *(reinterpret_cast<const float4*>(b1) + lane * 2);
        float4 bhi = *(reinterpret_cast<const float4*>(b1) + lane * 2 + 1);
        float bvals[8] = {blo.x, blo.y, blo.z, blo.w, bhi.x, bhi.y, bhi.z, bhi.w};
        for (int g = 0; g < 8; ++g) {
            int row = g * 8 + sub;
            int node = m0 + row;
            float h[8] = {};
            if (node < n) {
                float a[8] = {};
                uint2 v0 = *reinterpret_cast<const uint2*>(tab + (size_t)node * 256);
                acc_fp8x8(v0.x, v0.y, a);  // self term
                int e0 = rowptr[node], e1 = e0 + deg[node];
                int p = e0;
                for (; p + 16 <= e1; p += 16) {
                    int s[16];
                    #pragma unroll
                    for (int u = 0; u < 16; ++u) s[u] = csr_src[p + u];
                    uint2 w[16];
                    #pragma unroll
                    for (int u = 0; u < 16; ++u)
                        w[u] = *reinterpret_cast<const uint2*>(tab + (size_t)s[u] * 256);
                    #pragma unroll
                    for (int u = 0; u < 16; ++u)
                        acc_fp8x8(w[u].x, w[u].y, a);
                }
                if (p + 8 <= e1) {
                    int s[8];
                    #pragma unroll
                    for (int u = 0; u < 8; ++u) s[u] = csr_src[p + u];
                    uint2 w[8];
                    #pragma unroll
                    for (int u = 0; u < 8; ++u)
                        w[u] = *reinterpret_cast<const uint2*>(tab + (size_t)s[u] * 256);
                    #pragma unroll
                    for (int u = 0; u < 8; ++u)
                        acc_fp8x8(w[u].x, w[u].y, a);
                    p += 8;
                }
                for (; p < e1; ++p) {  // only on fallback (unpadded) CSR
                    int s = csr_src[p];
                    uint2 w = *reinterpret_cast<const uint2*>(tab + (size_t)s * 256);
                    acc_fp8x8(w.x, w.y, a);
                }
                float dv = dinv[node] * FP8_INVSCALE;
                #pragma unroll
                for (int j = 0; j < 8; ++j)
                    h[j] = fmaxf(fmaf(a[j], dv, bvals[j]), 0.f);
            }
            bf16x8 o;
            #pragma unroll
            for (int j = 0; j < 8; ++j) o[j] = (short)f2bf(h[j]);
            *reinterpret_cast<bf16x8*>(&As2[a2_idx(row, lane * 8)]) = o;
        }
    }
    __syncthreads();

    // ---- phase 2: MFMA K=256, N=128, B direct from W2F, no barriers ----
    const int wave = tid >> 6, lane = tid & 63;
    const int quad = lane >> 4, l16 = lane & 15;
    const int arow = wave * 16 + l16;
    f32x4 acc[2][4] = {};
    #pragma unroll
    for (int k0 = 0; k0 < 256; k0 += 32) {
        bf16x8 af = *reinterpret_cast<const bf16x8*>(&As2[a2_idx(arow, k0 + quad * 8)]);
        #pragma unroll
        for (int i = 0; i < 2; ++i) {
            #pragma unroll
            for (int ct = 0; ct < 4; ++ct) {
                bf16x8 bfr = *reinterpret_cast<const bf16x8*>(
                    W2F + ((((k0 >> 5) << 3) + i * 4 + ct) << 9) + lane * 8);
                acc[i][ct] = __builtin_amdgcn_mfma_f32_16x16x32_bf16(af, bfr, acc[i][ct], 0, 0, 0);
            }
        }
    }
    #pragma unroll
    for (int r = 0; r < 4; ++r) {
        int row = m0 + wave * 16 + quad * 4 + r;
        if (row < n) {
            float dv = dinv[row] * FP8_SCALE;
            #pragma unroll
            for (int i = 0; i < 2; ++i)
                #pragma unroll
                for (int ct = 0; ct < 4; ++ct)
                    hs2[(size_t)row * 128 + i * 64 + ct * 16 + l16] =
                        f2fp8(acc[i][ct][r] * dv);
        }
    }
}

// ---------- agg layer 2 + fused head (fp8 hs2, rows 128 B, 16 lanes/node) ----------
__global__ __launch_bounds__(256) void agg2_head_kernel(const unsigned char* __restrict__ hs,
                                                        const float* __restrict__ dinv,
                                                        const int* __restrict__ rowptr,
                                                        const int* __restrict__ deg,
                                                        const int* __restrict__ csr_src,
                                                        const float* __restrict__ bias,
                                                        const float* __restrict__ Wl,
                                                        const float* __restrict__ bl,
                                                        float* __restrict__ out, int n) {
    constexpr int LANES = 16, H = 128, NPB = 16;
    int sub = threadIdx.x / LANES;
    int lane = threadIdx.x % LANES;
    int node = blockIdx.x * NPB + sub;
    if (node >= n) return;
    const unsigned char* tab = hs + (size_t)lane * 8;
    float a[8] = {};
    uint2 v0 = *reinterpret_cast<const uint2*>(tab + (size_t)node * H);
    acc_fp8x8(v0.x, v0.y, a);  // self term
    int e0 = rowptr[node], e1 = e0 + deg[node];
    int p = e0;
    for (; p + 8 <= e1; p += 8) {
        int s[8];
        #pragma unroll
        for (int u = 0; u < 8; ++u) s[u] = csr_src[p + u];
        uint2 w[8];
        #pragma unroll
        for (int u = 0; u < 8; ++u)
            w[u] = *reinterpret_cast<const uint2*>(tab + (size_t)s[u] * H);
        #pragma unroll
        for (int u = 0; u < 8; ++u)
            acc_fp8x8(w[u].x, w[u].y, a);
    }
    for (; p < e1; ++p) {  // only on fallback CSR
        int s = csr_src[p];
        uint2 w = *reinterpret_cast<const uint2*>(tab + (size_t)s * H);
        acc_fp8x8(w.x, w.y, a);
    }
    float dv = dinv[node] * FP8_INVSCALE;
    float4 blo = *(reinterpret_cast<const float4*>(bias) + lane * 2);
    float4 bhi = *(reinterpret_cast<const float4*>(bias) + lane * 2 + 1);
    float bvals[8] = {blo.x, blo.y, blo.z, blo.w, bhi.x, bhi.y, bhi.z, bhi.w};
    float h[8];
    #pragma unroll
    for (int j = 0; j < 8; ++j)
        h[j] = fmaxf(fmaf(a[j], dv, bvals[j]), 0.f);
    float p0 = 0.f, p1 = 0.f, p2 = 0.f, p3 = 0.f;
    #pragma unroll
    for (int j = 0; j < 8; ++j) {
        float4 w = *reinterpret_cast<const float4*>(Wl + (size_t)(lane * 8 + j) * 4);
        p0 = fmaf(h[j], w.x, p0); p1 = fmaf(h[j], w.y, p1);
        p2 = fmaf(h[j], w.z, p2); p3 = fmaf(h[j], w.w, p3);
    }
    #pragma unroll
    for (int m = 1; m < 16; m <<= 1) {
        p0 += __shfl_xor(p0, m, 16);
        p1 += __shfl_xor(p1, m, 16);
        p2 += __shfl_xor(p2, m, 16);
        p3 += __shfl_xor(p3, m, 16);
    }
    if (lane == 0) {
        p0 += bl[0]; p1 += bl[1]; p2 += bl[2]; p3 += bl[3];
        float mx = fmaxf(fmaxf(p0, p1), fmaxf(p2, p3));
        float s = __expf(p0 - mx) + __expf(p1 - mx) + __expf(p2 - mx) + __expf(p3 - mx);
        float lse = mx + __logf(s);
        *(reinterpret_cast<float4*>(out) + node) = make_float4(p0 - lse, p1 - lse, p2 - lse, p3 - lse);
    }
}

// ---------- launch ----------
extern "C" void kernel_launch(void* const* d_in, const int* in_sizes, int n_in,
                              void* d_out, int out_size, void* d_ws, size_t ws_size,
                              hipStream_t stream) {
    const float* x  = (const float*)d_in[0];
    const int* eidx = (const int*)d_in[1];
    const float* W1 = (const float*)d_in[2];
    const float* b1 = (const float*)d_in[3];
    const float* W2 = (const float*)d_in[4];
    const float* b2 = (const float*)d_in[5];
    const float* Wl = (const float*)d_in[6];
    const float* bl = (const float*)d_in[7];
    float* out = (float*)d_out;

    const int n = in_sizes[0] / 512;
    const int E = in_sizes[1] / 2;
    const int nb = (n + BKT_NODES - 1) >> BKT_SHIFT;  // 196 for n=100000

    char* ws = (char*)d_ws;
    size_t off = 0;
    auto alloc = [&](size_t bytes) -> void* {
        void* p = ws + off;
        off += (bytes + 255) & ~(size_t)255;
        return p;
    };
    unsigned char*  hA  = (unsigned char*)alloc((size_t)(n + 1) * 256);  // hs1 fp8 + zero row
    unsigned char*  hB  = (unsigned char*)alloc((size_t)(n + 1) * 128);  // hs2 fp8 + zero row
    unsigned short* W1F = (unsigned short*)alloc((size_t)256 * 512 * 2);
    unsigned short* W2F = (unsigned short*)alloc((size_t)128 * 256 * 2);
    int* deg     = (int*)alloc((size_t)n * 4);
    int* rowptr  = (int*)alloc(((size_t)n + 1) * 4);
    int* cursor  = (int*)alloc((size_t)n * 4);
    float* dinv  = (float*)alloc((size_t)n * 4);
    int* csr_src = (int*)alloc(((size_t)E + (size_t)nb * BKT_PADMAX + 64) * 4);
    int* gcur    = (int*)alloc((size_t)nb * 4);
    size_t need_binned = off + (size_t)nb * BKT_CAP * 4 + 256;
    unsigned* binned = (unsigned*)alloc((size_t)nb * BKT_CAP * 4);

    if (need_binned <= ws_size && nb <= 256 && n < (1 << 23)) {
        hipMemsetAsync(gcur, 0, (size_t)nb * 4, stream);
        int ntiles = (E + BIN_TILE - 1) / BIN_TILE;
        int bgrid = ntiles < 1024 ? ntiles : 1024;
        bin_kernel<<<dim3(bgrid), dim3(256), 0, stream>>>(eidx, E, nb, ntiles, gcur, binned);
        csr_build_kernel<<<dim3(nb), dim3(256), 0, stream>>>(binned, gcur, rowptr, deg, dinv,
                                                             csr_src, nb, n);
    } else {
        hipMemsetAsync(deg, 0, (size_t)n * 4, stream);
        hist_kernel<<<dim3(1024), dim3(256), 0, stream>>>(eidx + E, E, deg);
        scan_kernel<<<dim3(1), dim3(256), 0, stream>>>(deg, rowptr, n);
        dinv_kernel<<<dim3((n + 255) / 256), dim3(256), 0, stream>>>(deg, dinv, n);
        hipMemcpyAsync(cursor, rowptr, (size_t)n * 4, hipMemcpyDeviceToDevice, stream);
        fill_kernel<<<dim3((E + 255) / 256), dim3(256), 0, stream>>>(eidx, E, cursor, csr_src);
    }

    // Weight fragment-pack + sentinel-row zeroing (single launch)
    wt_kernel<<<dim3((512 * 256 + 256 * 128 + 255) / 256), dim3(256), 0, stream>>>(
        W1, W2, W1F, W2F, hA + (size_t)n * 256, hB + (size_t)n * 128);

    const int mblocks = (n + 63) / 64;

    // Layer 1 GEMM: hs1 = fp8((x@W1)*dinv*64)   (3-buf counted-vmcnt pipeline)
    gemm1_kernel<<<dim3(mblocks), dim3(256), 0, stream>>>(x, W1F, dinv, hA, n);

    // Fused agg1 + gemm2: hs2 = fp8((relu(agg(hs1))@W2)*dinv*64)
    agg1_gemm2_kernel<<<dim3(mblocks), dim3(256), 0, stream>>>(
        hA, dinv, rowptr, deg, csr_src, b1, W2F, hB, n);

    // agg2 + head fused (fp8 gather)
    agg2_head_kernel<<<dim3((n + 15) / 16), dim3(256), 0, stream>>>(
        hB, dinv, rowptr, deg, csr_src, b2, Wl, bl, out, n);
}